// Round 6
// baseline (58.523 us; speedup 1.0000x reference)
//
#include <hip/hip_runtime.h>
#include <hip/hip_bf16.h>
#include <stdint.h>

// Problem: B=32, N=4096, D=256, F=256
//   x = relu(A @ W + bias)            A:[B,F] W:[F,N] -> x:[B,N]
//   mask = x > threshold
//   out[b] = stable-compact(raw_input[b] rows where mask), zero-padded to N.
//
// Kernel 1: tiny GEMM -> packed bit-mask bytes [B][512] (read back as u16).
// Kernel 2: fused per-block scan + gather, 64 dst rows per block, 512 thr.
//           PLAIN stores (the 7 TB/s harness fills use plain stores; NT
//           stores are the prime suspect for gather's 2.6 TB/s), NT loads.

#define BB 32
#define NN 4096
#define DD 256
#define FF 256
#define ASTRIDE (FF + 4)   // padded LDS stride
#define RPB 64             // gather: dst rows per block (8 waves x 8)

typedef float f4 __attribute__((ext_vector_type(4)));

// ---------------- Kernel 1: tiny GEMM -> packed masks -----------------------
// Grid 512 blocks x 256 threads; block owns 8 columns x all 32 batches.
// W read exactly once from HBM. f64 accumulation keeps the mask exact vs the
// f32 reference (validated absmax=0 in R2-R5).
__global__ __launch_bounds__(256) void mask_kernel(
    const float* __restrict__ A,      // [B,F]
    const float* __restrict__ W,      // [F,N]
    const float* __restrict__ bias,   // [N]
    const float* __restrict__ thr_p,  // [1]
    uint8_t* __restrict__ bits8)      // [B][512]
{
    __shared__ float a_sh[BB * ASTRIDE];
    __shared__ float wT[8 * ASTRIDE];

    const int t     = threadIdx.x;
    const int chunk = blockIdx.x;          // 0..511
    const int n0    = chunk * 8;

    for (int i = t; i < BB * FF; i += 256) {
        int b = i >> 8, f = i & 255;
        a_sh[b * ASTRIDE + f] = A[i];
    }
    for (int i = t; i < FF * 8; i += 256) {
        int f = i >> 3, c = i & 7;
        wT[c * ASTRIDE + f] = W[(size_t)f * NN + n0 + c];
    }
    __syncthreads();

    const float thr = thr_p[0];
    const int c = t & 7;
    const int b = t >> 3;

    const f4* ap = reinterpret_cast<const f4*>(a_sh + b * ASTRIDE);
    const f4* wp = reinterpret_cast<const f4*>(wT   + c * ASTRIDE);

    double s0 = 0.0, s1 = 0.0, s2 = 0.0, s3 = 0.0;
    #pragma unroll 8
    for (int fs = 0; fs < FF / 4; ++fs) {
        f4 a4 = ap[fs];
        f4 w4 = wp[fs];
        s0 = fma((double)a4.x, (double)w4.x, s0);
        s1 = fma((double)a4.y, (double)w4.y, s1);
        s2 = fma((double)a4.z, (double)w4.z, s2);
        s3 = fma((double)a4.w, (double)w4.w, s3);
    }
    const float v = (float)((s0 + s1) + (s2 + s3)) + bias[n0 + c];
    const int m = (fmaxf(v, 0.f) > thr) ? 1 : 0;

    unsigned long long bal = __ballot(m);
    if (c == 0) {
        const int g = (t & 63) >> 3;
        bits8[b * 512 + chunk] = (uint8_t)((bal >> (8 * g)) & 0xFF);
    }
}

// ---------------- Kernel 2: fused scan + gather ------------------------------
// Grid (N/RPB = 64, B) = 2048 blocks x 512 threads. First 256 threads scan the
// batch's 256 u16 chunks (512 B, L2-resident) and expand this block's 64-row
// dst window into LDS; then 8 waves each copy/zero 8 rows (batched loads,
// then plain stores).
__global__ __launch_bounds__(512) void gather_kernel(
    const float* __restrict__ raw,     // [B,N,D]
    const uint16_t* __restrict__ bits, // [B][256]
    float* __restrict__ out)           // [B,N,D]
{
    const int b   = blockIdx.y;
    const int t   = threadIdx.x;
    const int j0b = blockIdx.x * RPB;

    __shared__ int wsum[4];
    __shared__ int cnt_sh;
    __shared__ int order_sh[RPB];

    if (t < 256) {
        // --- scan over packed mask (thread t owns chunk t, 16 cols) ---
        unsigned m = bits[b * 256 + t];
        const int s = __popc(m);

        const int lane4 = t & 63;
        const int wid4  = t >> 6;        // 0..3
        int incl = s;
        #pragma unroll
        for (int d = 1; d < 64; d <<= 1) {
            int x = __shfl_up(incl, d, 64);
            if (lane4 >= d) incl += x;
        }
        if (lane4 == 63) wsum[wid4] = incl;
        __syncthreads();
        if (t == 0) {
            int run = 0;
            #pragma unroll
            for (int i = 0; i < 4; ++i) { int x = wsum[i]; wsum[i] = run; run += x; }
            cnt_sh = run;
        }
        __syncthreads();

        int base = wsum[wid4] + (incl - s);   // stable exclusive prefix
        if (base < j0b + RPB && base + s > j0b) {
            const int n0 = t * 16;
            while (m) {
                const int pos = __ffs(m) - 1;
                const unsigned rel = (unsigned)(base - j0b);
                if (rel < RPB) order_sh[rel] = n0 + pos;
                ++base;
                if (base >= j0b + RPB) break;
                m &= m - 1;
            }
        }
    } else {
        __syncthreads();
        __syncthreads();
    }
    __syncthreads();

    // --- gather/zero: wave wid owns rows j0b + wid*8 .. +7 ---
    const int cnt  = cnt_sh;
    const int lane = t & 63;
    const int wid  = t >> 6;             // 0..7
    const f4* rawb = reinterpret_cast<const f4*>(raw) + (size_t)b * NN * (DD / 4);
    f4*       outb = reinterpret_cast<f4*>(out)       + (size_t)b * NN * (DD / 4);
    const int j0 = j0b + wid * 8;
    const int rr = j0 - j0b;

    f4 v0 = {0.f, 0.f, 0.f, 0.f}, v1 = v0, v2 = v0, v3 = v0;
    f4 v4 = v0, v5 = v0, v6 = v0, v7 = v0;
    if (j0 + 0 < cnt) v0 = __builtin_nontemporal_load(&rawb[(size_t)order_sh[rr + 0] * (DD / 4) + lane]);
    if (j0 + 1 < cnt) v1 = __builtin_nontemporal_load(&rawb[(size_t)order_sh[rr + 1] * (DD / 4) + lane]);
    if (j0 + 2 < cnt) v2 = __builtin_nontemporal_load(&rawb[(size_t)order_sh[rr + 2] * (DD / 4) + lane]);
    if (j0 + 3 < cnt) v3 = __builtin_nontemporal_load(&rawb[(size_t)order_sh[rr + 3] * (DD / 4) + lane]);
    if (j0 + 4 < cnt) v4 = __builtin_nontemporal_load(&rawb[(size_t)order_sh[rr + 4] * (DD / 4) + lane]);
    if (j0 + 5 < cnt) v5 = __builtin_nontemporal_load(&rawb[(size_t)order_sh[rr + 5] * (DD / 4) + lane]);
    if (j0 + 6 < cnt) v6 = __builtin_nontemporal_load(&rawb[(size_t)order_sh[rr + 6] * (DD / 4) + lane]);
    if (j0 + 7 < cnt) v7 = __builtin_nontemporal_load(&rawb[(size_t)order_sh[rr + 7] * (DD / 4) + lane]);

    outb[(size_t)(j0 + 0) * (DD / 4) + lane] = v0;
    outb[(size_t)(j0 + 1) * (DD / 4) + lane] = v1;
    outb[(size_t)(j0 + 2) * (DD / 4) + lane] = v2;
    outb[(size_t)(j0 + 3) * (DD / 4) + lane] = v3;
    outb[(size_t)(j0 + 4) * (DD / 4) + lane] = v4;
    outb[(size_t)(j0 + 5) * (DD / 4) + lane] = v5;
    outb[(size_t)(j0 + 6) * (DD / 4) + lane] = v6;
    outb[(size_t)(j0 + 7) * (DD / 4) + lane] = v7;
}

extern "C" void kernel_launch(void* const* d_in, const int* in_sizes, int n_in,
                              void* d_out, int out_size, void* d_ws, size_t ws_size,
                              hipStream_t stream) {
    const float* raw  = (const float*)d_in[0];   // [B,N,D]
    const float* A    = (const float*)d_in[1];   // [B,F]
    const float* W    = (const float*)d_in[2];   // [F,N]
    const float* bias = (const float*)d_in[3];   // [N]
    const float* thr  = (const float*)d_in[4];   // [1]
    float* out = (float*)d_out;

    uint8_t* bits8 = (uint8_t*)d_ws;             // B*512 = 16 KB

    mask_kernel<<<512, 256, 0, stream>>>(A, W, bias, thr, bits8);
    gather_kernel<<<dim3(NN / RPB, BB), 512, 0, stream>>>(
        raw, (const uint16_t*)bits8, out);
}